// Round 5
// baseline (351.780 us; speedup 1.0000x reference)
//
#include <hip/hip_runtime.h>
#include <hip/hip_bf16.h>

// BasicIcoS2SUpBlock — R5: cv-merged convA, all-NHWC intermediates (full-line
// stores), smaller tiles for occupancy, 14-slot (no dummy) phase weights.
// R4 lesson: convA latency-bound (MfmaUtil 11%, VALU 19%, HBM 23%, Occ 18%)
// -> scattered 2B NCHW stores + double staging were the stall.

#define CIN   64
#define COUT  32
#define HX    160
#define WX    64
#define HY    320
#define WY    128
#define NB    16
#define BN_EPS 1e-5f

typedef short s16x8 __attribute__((ext_vector_type(8)));
typedef float f32x4 __attribute__((ext_vector_type(4)));

__device__ inline void store_bf16x4(__hip_bfloat16* p, f32x4 v) {
    union { unsigned long long u; __hip_bfloat162 h[2]; } pk;
    pk.h[0] = __float22bfloat162_rn(make_float2(v[0], v[1]));
    pk.h[1] = __float22bfloat162_rn(make_float2(v[2], v[3]));
    *(unsigned long long*)p = pk.u;
}

// ---------------------------------------------------------------------------
// prep_x: x NCHW fp32 -> xt NHWC bf16 ([n][row160][col64][ci64], ci contig)
// ---------------------------------------------------------------------------
__global__ __launch_bounds__(256) void prep_x(const float* __restrict__ x,
                                              __hip_bfloat16* __restrict__ xt)
{
    __shared__ float tile[64][65];
    const int n  = blockIdx.y;
    const int p0 = blockIdx.x * 64;
    const int t  = threadIdx.x;
#pragma unroll
    for (int e = 0; e < 16; ++e) {
        int k = e * 256 + t;
        int ci = k >> 6, p = k & 63;
        tile[ci][p] = x[(n * CIN + ci) * (HX * WX) + p0 + p];
    }
    __syncthreads();
#pragma unroll
    for (int e = 0; e < 16; ++e) {
        int k = e * 256 + t;
        int p = k >> 6, ci = k & 63;
        xt[((size_t)n * (HX * WX) + p0 + p) * 64 + ci] = __float2bfloat16(tile[ci][p]);
    }
}

// ---------------------------------------------------------------------------
// prep_w: effective phase weights (bf16), 14 real slots (4/3/3/4 per phase).
// wAb: [cv(2)][slot(14)][co(32)][ci(64)]
// wBb: [tap(7)][co(32)][ci(32)]
// ---------------------------------------------------------------------------
__global__ __launch_bounds__(256) void prep_w(const float* __restrict__ w00,
                                              const float* __restrict__ w01,
                                              const float* __restrict__ w10,
                                              __hip_bfloat16* __restrict__ wAb,
                                              __hip_bfloat16* __restrict__ wBb)
{
    int t = blockIdx.x * 256 + threadIdx.x;
    if (t < 4096) {                       // convA weights
        int cv = t >> 11, u = t & 2047;
        int co = u >> 6, ci = u & 63;
        const float* w = (cv ? w10 : w00) + (co * 64 + ci) * 9;
        float a = w[0], b = w[1], c = w[3], d = w[4], e5 = w[5], f = w[7], g = w[8];
        float v[14];
        v[0] = a;              v[1] = b;          v[2] = c;      v[3] = d + e5 + f + g;
        v[4] = a + b;          v[5] = c + d + f;  v[6] = e5 + g;
        v[7] = a + c;          v[8] = b + d + e5; v[9] = f + g;
        v[10] = a + b + c + d; v[11] = e5;        v[12] = f;     v[13] = g;
#pragma unroll
        for (int s = 0; s < 14; ++s)
            wAb[(((size_t)cv * 14 + s) * 32 + co) * 64 + ci] = __float2bfloat16(v[s]);
    } else if (t < 5120) {                // convB weights (hex taps of 3x3)
        int u = t - 4096;
        int co = u >> 5, ci = u & 31;
        const float* w = w01 + (co * 32 + ci) * 9;
        const int wi[7] = {0, 1, 3, 4, 5, 7, 8};
#pragma unroll
        for (int s = 0; s < 7; ++s)
            wBb[((size_t)s * 32 + co) * 32 + ci] = __float2bfloat16(w[wi[s]]);
    }
}

// ---------------------------------------------------------------------------
// convA: conv00 + conv10 from one staged tile (cv-merged), phase-decomposed.
// Block: 8x16 x-tile -> 16x32 output px, all 32 co, both convs.
// LDS x-tile [10][18][ci64 pad72] bf16 = 25.9 KB. Outputs NHWC bf16 (full
// 64B-line stores). Partial stats -> pA[cv*1280 + blk][64].
// ---------------------------------------------------------------------------
__global__ __launch_bounds__(256) void convA(
    const __hip_bfloat16* __restrict__ xt, const __hip_bfloat16* __restrict__ wAb,
    __hip_bfloat16* __restrict__ y0h, __hip_bfloat16* __restrict__ y1h,
    float* __restrict__ partialsA)
{
    __shared__ short lds[180 * 72];            // 25920 B
    const int tb = blockIdx.x & 3, ta = blockIdx.x >> 2;   // ta 0..19, tb 0..3
    const int nb = blockIdx.y;
    const int t = threadIdx.x, wave = t >> 6, lane = t & 63;
    const int n = lane & 15, q = lane >> 4;
    const int a0 = ta * 8, b0 = tb * 16;

    // ---- stage x tile (rows wrap mod 160, cols zero-pad) ----
    for (int idx = t; idx < 1440; idx += 256) {       // 180 chunks * 8 lanes
        int chunk = idx >> 3, sub = idx & 7;
        int rl = chunk / 18, cl = chunk - rl * 18;
        int grow = a0 - 1 + rl;
        if (grow < 0) grow += HX; else if (grow >= HX) grow -= HX;
        int gcol = b0 - 1 + cl;
        uint4 v = make_uint4(0u, 0u, 0u, 0u);
        if ((unsigned)gcol < (unsigned)WX)
            v = *(const uint4*)(xt + (((size_t)nb * HX + grow) * WX + gcol) * 64 + sub * 8);
        *(uint4*)(&lds[chunk * 72 + sub * 8]) = v;
    }
    __syncthreads();

    // per-phase tap slots (4/3/3/4), shifts
    const int off14[5] = {0, 4, 7, 10, 14};
    const int dr14[14] = {-1,-1, 0, 0,  -1, 0, 0,   0, 0, 1,   0, 0, 1, 1};
    const int dc14[14] = {-1, 0,-1, 0,   0, 0, 1,  -1, 0, 0,   0, 1, 0, 1};

    f32x4 st[2][2], sq[2][2];                 // [cv][h], vector over r
#pragma unroll
    for (int cv = 0; cv < 2; ++cv)
#pragma unroll
        for (int h = 0; h < 2; ++h) {
            st[cv][h] = (f32x4){0.f, 0.f, 0.f, 0.f};
            sq[cv][h] = (f32x4){0.f, 0.f, 0.f, 0.f};
        }

#pragma unroll
    for (int ph = 0; ph < 4; ++ph) {
        const int pa = ph >> 1, pb = ph & 1;
        const int s0 = off14[ph], s1 = off14[ph + 1];
#pragma unroll
        for (int rr = 0; rr < 2; ++rr) {
            const int rl = wave * 2 + rr;
            s16x8 B[4][2];
#pragma unroll
            for (int s = s0; s < s1; ++s) {
                const int o = ((rl + 1 + dr14[s]) * 18 + (n + 1 + dc14[s])) * 72;
                B[s - s0][0] = *(const s16x8*)(&lds[o + q * 8]);
                B[s - s0][1] = *(const s16x8*)(&lds[o + 32 + q * 8]);
            }
            f32x4 acc[2][2];
#pragma unroll
            for (int cv = 0; cv < 2; ++cv)
#pragma unroll
                for (int h = 0; h < 2; ++h) acc[cv][h] = (f32x4){0.f, 0.f, 0.f, 0.f};
#pragma unroll
            for (int cv = 0; cv < 2; ++cv)
#pragma unroll
                for (int s = s0; s < s1; ++s)
#pragma unroll
                    for (int kc = 0; kc < 2; ++kc)
#pragma unroll
                        for (int h = 0; h < 2; ++h) {
                            s16x8 A = *(const s16x8*)(wAb +
                                (((size_t)cv * 14 + s) * 32 + h * 16 + n) * 64 + kc * 32 + q * 8);
                            acc[cv][h] = __builtin_amdgcn_mfma_f32_16x16x32_bf16(
                                A, B[s - s0][kc], acc[cv][h], 0, 0, 0);
                        }
            const int i = 2 * (a0 + rl) + pa;
            const int j = 2 * b0 + pb + 2 * n;
            const size_t obase = ((((size_t)nb * HY + i) * WY + j) * 32) + q * 4;
#pragma unroll
            for (int cv = 0; cv < 2; ++cv) {
                __hip_bfloat16* yp = cv ? y1h : y0h;
#pragma unroll
                for (int h = 0; h < 2; ++h) {
                    store_bf16x4(yp + obase + h * 16, acc[cv][h]);
                    st[cv][h] += acc[cv][h];
                    sq[cv][h] += acc[cv][h] * acc[cv][h];
                }
            }
        }
    }

    // ---- per-block stats reduction ----
    __syncthreads();
    float* scr = (float*)lds;                 // [wave4][cv2][co32][which2]
#pragma unroll
    for (int cv = 0; cv < 2; ++cv)
#pragma unroll
        for (int h = 0; h < 2; ++h)
#pragma unroll
            for (int r = 0; r < 4; ++r) {
                float s = st[cv][h][r], qv = sq[cv][h][r];
#pragma unroll
                for (int m = 1; m < 16; m <<= 1) {
                    s  += __shfl_xor(s, m, 16);
                    qv += __shfl_xor(qv, m, 16);
                }
                if (n == 0) {
                    const int co = h * 16 + q * 4 + r;
                    scr[(((wave * 2 + cv) * 32) + co) * 2]     = s;
                    scr[(((wave * 2 + cv) * 32) + co) * 2 + 1] = qv;
                }
            }
    __syncthreads();
    if (t < 128) {
        const int cv = t >> 6, which = (t >> 5) & 1, co = t & 31;
        float s = 0.f;
#pragma unroll
        for (int w = 0; w < 4; ++w)
            s += scr[(((w * 2 + cv) * 32) + co) * 2 + which];
        const int blk = nb * 80 + blockIdx.x;          // 0..1279
        partialsA[((size_t)cv * 1280 + blk) * 64 + which * 32 + co] = s;
    }
}

// ---------------------------------------------------------------------------
// reduce16: block b reduces src[b*16 .. b*16+15][64] -> dst[b][64]
// ---------------------------------------------------------------------------
__global__ __launch_bounds__(256) void reduce16(const float* __restrict__ src,
                                                float* __restrict__ dst)
{
    __shared__ float red[4][64];
    const int t = threadIdx.x, c = t & 63, seg = t >> 6;
    const float* s = src + (size_t)blockIdx.x * 16 * 64;
    float acc = 0.f;
#pragma unroll
    for (int r = 0; r < 4; ++r) acc += s[(seg + r * 4) * 64 + c];
    red[seg][c] = acc;
    __syncthreads();
    if (t < 64)
        dst[(size_t)blockIdx.x * 64 + t] = red[0][t] + red[1][t] + red[2][t] + red[3][t];
}

// ---------------------------------------------------------------------------
// params_h: redA rows 0..79 (conv00) -> BN scale/shift for h. phs: [s32, t32]
// ---------------------------------------------------------------------------
__global__ void params_h_kernel(const float* __restrict__ redA,
                                const float* __restrict__ g00,
                                const float* __restrict__ b00,
                                float* __restrict__ phs)
{
    __shared__ float tot[64];
    const int t = threadIdx.x;
    float s = 0.f;
    for (int b = 0; b < 80; ++b) s += redA[b * 64 + t];
    tot[t] = s;
    __syncthreads();
    if (t < 32) {
        const float nf = (float)(NB * HY * WY);
        float mean = tot[t] / nf;
        float var  = tot[32 + t] / nf - mean * mean;
        float sc = g00[t] * rsqrtf(var + BN_EPS);
        phs[t] = sc;
        phs[32 + t] = b00[t] - mean * sc;
    }
}

// ---------------------------------------------------------------------------
// convB: conv01 on h = relu(bn(y0)) (BN+ReLU fused into bf16 staging).
// Block: 8x32 out-tile, all 32 co. LDS [10][34][ci32 pad40] = 27.2 KB.
// Output y2 NHWC bf16 (full-line stores). Partials -> pB[blk][64].
// ---------------------------------------------------------------------------
__global__ __launch_bounds__(256) void convB(
    const __hip_bfloat16* __restrict__ y0h, const __hip_bfloat16* __restrict__ wBb,
    const float* __restrict__ phs, __hip_bfloat16* __restrict__ y2h,
    float* __restrict__ partialsB)
{
    __shared__ short lds[340 * 40];            // 27200 B
    const int tj = blockIdx.x & 3, ti = blockIdx.x >> 2;   // ti 0..39, tj 0..3
    const int nb = blockIdx.y;
    const int t = threadIdx.x, wave = t >> 6, lane = t & 63;
    const int n = lane & 15, q = lane >> 4;
    const int i0 = ti * 8, j0 = tj * 32;

    // BN params for this thread's staged ci octet (sub = t&3 stays fixed)
    const int cis = (t & 3) * 8;
    float sv[8], tv[8];
#pragma unroll
    for (int e = 0; e < 8; ++e) { sv[e] = phs[cis + e]; tv[e] = phs[32 + cis + e]; }

    // ---- stage h tile ----
    for (int idx = t; idx < 1360; idx += 256) {      // 340 chunks * 4 lanes
        int chunk = idx >> 2, sub = idx & 3;
        int rl = chunk / 34, cl = chunk - rl * 34;
        int grow = i0 - 1 + rl;
        if (grow < 0) grow += HY; else if (grow >= HY) grow -= HY;
        int gcol = j0 - 1 + cl;
        uint4 w = make_uint4(0u, 0u, 0u, 0u);
        if ((unsigned)gcol < (unsigned)WY) {
            uint4 v = *(const uint4*)(y0h + (((size_t)nb * HY + grow) * WY + gcol) * 32 + sub * 8);
            unsigned* vi = (unsigned*)&v;
            unsigned* wi = (unsigned*)&w;
#pragma unroll
            for (int k = 0; k < 4; ++k) {
                unsigned u = vi[k];
                float f0 = __uint_as_float(u << 16);
                float f1 = __uint_as_float(u & 0xffff0000u);
                f0 = fmaxf(fmaf(f0, sv[2 * k], tv[2 * k]), 0.f);
                f1 = fmaxf(fmaf(f1, sv[2 * k + 1], tv[2 * k + 1]), 0.f);
                union { __hip_bfloat162 b2; unsigned u32; } cvt;
                cvt.b2 = __float22bfloat162_rn(make_float2(f0, f1));
                wi[k] = cvt.u32;
            }
        }
        *(uint4*)(&lds[chunk * 40 + sub * 8]) = w;
    }
    __syncthreads();

    // A fragments [tap][h] (persist: 14 x 4 VGPRs)
    s16x8 A[7][2];
#pragma unroll
    for (int s = 0; s < 7; ++s)
#pragma unroll
        for (int h = 0; h < 2; ++h)
            A[s][h] = *(const s16x8*)(wBb + ((size_t)s * 32 + h * 16 + n) * 32 + q * 8);

    const int dr7[7] = {-1, -1, 0, 0, 0, 1, 1};
    const int dc7[7] = {-1,  0,-1, 0, 1, 0, 1};

    f32x4 st[2], sq[2];
    st[0] = st[1] = (f32x4){0.f, 0.f, 0.f, 0.f};
    sq[0] = sq[1] = (f32x4){0.f, 0.f, 0.f, 0.f};

#pragma unroll
    for (int rr = 0; rr < 2; ++rr) {
        const int rl = wave * 2 + rr;
#pragma unroll
        for (int cg = 0; cg < 2; ++cg) {
            s16x8 B[7];
#pragma unroll
            for (int s = 0; s < 7; ++s)
                B[s] = *(const s16x8*)(&lds[((rl + 1 + dr7[s]) * 34 +
                                             (cg * 16 + n + 1 + dc7[s])) * 40 + q * 8]);
            f32x4 acc[2];
            acc[0] = (f32x4){0.f, 0.f, 0.f, 0.f};
            acc[1] = (f32x4){0.f, 0.f, 0.f, 0.f};
#pragma unroll
            for (int s = 0; s < 7; ++s)
#pragma unroll
                for (int h = 0; h < 2; ++h)
                    acc[h] = __builtin_amdgcn_mfma_f32_16x16x32_bf16(
                        A[s][h], B[s], acc[h], 0, 0, 0);
            const int i = i0 + rl;
            const int j = j0 + cg * 16 + n;
            const size_t obase = ((((size_t)nb * HY + i) * WY + j) * 32) + q * 4;
#pragma unroll
            for (int h = 0; h < 2; ++h) {
                store_bf16x4(y2h + obase + h * 16, acc[h]);
                st[h] += acc[h];
                sq[h] += acc[h] * acc[h];
            }
        }
    }

    __syncthreads();
    float* scr = (float*)lds;                 // [wave4][co32][which2]
#pragma unroll
    for (int h = 0; h < 2; ++h)
#pragma unroll
        for (int r = 0; r < 4; ++r) {
            float s = st[h][r], qv = sq[h][r];
#pragma unroll
            for (int m = 1; m < 16; m <<= 1) {
                s  += __shfl_xor(s, m, 16);
                qv += __shfl_xor(qv, m, 16);
            }
            if (n == 0) {
                const int co = h * 16 + q * 4 + r;
                scr[(wave * 32 + co) * 2]     = s;
                scr[(wave * 32 + co) * 2 + 1] = qv;
            }
        }
    __syncthreads();
    if (t < 64) {
        const int co = t & 31, which = t >> 5;
        float s = 0.f;
#pragma unroll
        for (int w = 0; w < 4; ++w) s += scr[(w * 32 + co) * 2 + which];
        const int blk = nb * 160 + blockIdx.x;          // 0..2559
        partialsB[(size_t)blk * 64 + which * 32 + co] = s;
    }
}

// ---------------------------------------------------------------------------
// params_final: redA rows 80..159 (conv10) + redB rows 0..159 (conv01) -> pf
// pf: [s1[32], t1[32], s2[32], t2[32]]
// ---------------------------------------------------------------------------
__global__ void params_final_kernel(const float* __restrict__ redA,
                                    const float* __restrict__ redB,
                                    const float* __restrict__ g01,
                                    const float* __restrict__ b01,
                                    const float* __restrict__ g10,
                                    const float* __restrict__ b10,
                                    float* __restrict__ pf)
{
    __shared__ float tot1[64], tot2[64];
    const int t = threadIdx.x;
    float s1 = 0.f, s2 = 0.f;
    for (int b = 0; b < 80; ++b)  s1 += redA[(80 + b) * 64 + t];
    for (int b = 0; b < 160; ++b) s2 += redB[b * 64 + t];
    tot1[t] = s1; tot2[t] = s2;
    __syncthreads();
    if (t < 32) {
        const float nf = (float)(NB * HY * WY);
        float m1 = tot1[t] / nf;
        float v1 = tot1[32 + t] / nf - m1 * m1;
        float sc1 = g10[t] * rsqrtf(v1 + BN_EPS);
        pf[t] = sc1;
        pf[32 + t] = b10[t] - m1 * sc1;
        float m2 = tot2[t] / nf;
        float v2 = tot2[32 + t] / nf - m2 * m2;
        float sc2 = g01[t] * rsqrtf(v2 + BN_EPS);
        pf[64 + t] = sc2;
        pf[96 + t] = b01[t] - m2 * sc2;
    }
}

// ---------------------------------------------------------------------------
// final: out = relu(bn(y2) + bn(y1)) with NHWC->NCHW transpose via LDS.
// Block: (nb, 2 rows); reads y1h/y2h NHWC coalesced, writes out NCHW float4.
// ---------------------------------------------------------------------------
__global__ __launch_bounds__(256) void final_kernel(
    const __hip_bfloat16* __restrict__ y1h, const __hip_bfloat16* __restrict__ y2h,
    const float* __restrict__ pf, float* __restrict__ out)
{
    __shared__ float ldsf[32 * 132];
    const int nb = blockIdx.y;
    const int i0 = blockIdx.x * 2;
    const int t = threadIdx.x;
    const int c8 = (t & 3) * 8;                 // this thread's co octet (fixed)

    float P1s[8], P1t[8], P2s[8], P2t[8];
#pragma unroll
    for (int e = 0; e < 8; ++e) {
        P1s[e] = pf[c8 + e];      P1t[e] = pf[32 + c8 + e];
        P2s[e] = pf[64 + c8 + e]; P2t[e] = pf[96 + c8 + e];
    }

    for (int row = 0; row < 2; ++row) {
        const int i = i0 + row;
        const size_t base = (((size_t)nb * HY + i) * WY) * 32;
        if (row) __syncthreads();
#pragma unroll
        for (int rep = 0; rep < 2; ++rep) {
            const int idx = rep * 256 + t;      // 0..511
            const int j = idx >> 2;             // 0..127
            uint4 a = *(const uint4*)(y2h + base + (size_t)j * 32 + c8);
            uint4 d = *(const uint4*)(y1h + base + (size_t)j * 32 + c8);
            const unsigned* ai = (const unsigned*)&a;
            const unsigned* di = (const unsigned*)&d;
#pragma unroll
            for (int k = 0; k < 4; ++k) {
                float a0 = __uint_as_float(ai[k] << 16);
                float a1 = __uint_as_float(ai[k] & 0xffff0000u);
                float d0 = __uint_as_float(di[k] << 16);
                float d1 = __uint_as_float(di[k] & 0xffff0000u);
                float r0 = fmaf(a0, P2s[2 * k], P2t[2 * k]) + fmaf(d0, P1s[2 * k], P1t[2 * k]);
                float r1 = fmaf(a1, P2s[2 * k + 1], P2t[2 * k + 1]) + fmaf(d1, P1s[2 * k + 1], P1t[2 * k + 1]);
                ldsf[(c8 + 2 * k) * 132 + j]     = r0 > 0.f ? r0 : 0.f;
                ldsf[(c8 + 2 * k + 1) * 132 + j] = r1 > 0.f ? r1 : 0.f;
            }
        }
        __syncthreads();
#pragma unroll
        for (int rep = 0; rep < 4; ++rep) {
            const int idx = rep * 256 + t;      // 0..1023
            const int co = idx >> 5, jg = (idx & 31) * 4;
            float4 v = *(float4*)(&ldsf[co * 132 + jg]);
            *(float4*)(out + (((size_t)nb * 32 + co) * HY + i) * WY + jg) = v;
        }
    }
}

// ---------------------------------------------------------------------------
extern "C" void kernel_launch(void* const* d_in, const int* in_sizes, int n_in,
                              void* d_out, int out_size, void* d_ws, size_t ws_size,
                              hipStream_t stream)
{
    (void)in_sizes; (void)n_in; (void)out_size; (void)ws_size;
    const float* x   = (const float*)d_in[0];
    const float* w00 = (const float*)d_in[1];
    const float* w01 = (const float*)d_in[2];
    const float* w10 = (const float*)d_in[3];
    const float* g00 = (const float*)d_in[4];
    const float* b00 = (const float*)d_in[5];
    const float* g01 = (const float*)d_in[6];
    const float* b01 = (const float*)d_in[7];
    const float* g10 = (const float*)d_in[8];
    const float* b10 = (const float*)d_in[9];
    float* out = (float*)d_out;

    // workspace (byte offsets, all 256B-aligned)
    char* ws = (char*)d_ws;
    const size_t NPLANE = (size_t)NB * COUT * HY * WY;       // 20,971,520
    __hip_bfloat16* y1h  = (__hip_bfloat16*)ws;               ws += NPLANE * 2;
    __hip_bfloat16* y2h  = (__hip_bfloat16*)ws;               ws += NPLANE * 2;
    __hip_bfloat16* y0h  = (__hip_bfloat16*)ws;               ws += NPLANE * 2;
    __hip_bfloat16* xt   = (__hip_bfloat16*)ws;               ws += (size_t)NB * CIN * HX * WX * 2;
    __hip_bfloat16* wAb  = (__hip_bfloat16*)ws;               ws += 2 * 14 * 32 * 64 * 2;
    __hip_bfloat16* wBb  = (__hip_bfloat16*)ws;               ws += 7 * 32 * 32 * 2;
    float*          pA   = (float*)ws;                        ws += 2 * 1280 * 64 * 4;
    float*          pB   = (float*)ws;                        ws += 2560 * 64 * 4;
    float*          redA = (float*)ws;                        ws += 160 * 64 * 4;
    float*          redB = (float*)ws;                        ws += 160 * 64 * 4;
    float*          phs  = (float*)ws;                        ws += 256;
    float*          pf   = (float*)ws;

    prep_x<<<dim3(160, 16), dim3(256), 0, stream>>>(x, xt);
    prep_w<<<dim3(20), dim3(256), 0, stream>>>(w00, w01, w10, wAb, wBb);
    convA<<<dim3(80, 16), dim3(256), 0, stream>>>(xt, wAb, y0h, y1h, pA);
    reduce16<<<dim3(160), dim3(256), 0, stream>>>(pA, redA);
    params_h_kernel<<<dim3(1), dim3(64), 0, stream>>>(redA, g00, b00, phs);
    convB<<<dim3(160, 16), dim3(256), 0, stream>>>(y0h, wBb, phs, y2h, pB);
    reduce16<<<dim3(160), dim3(256), 0, stream>>>(pB, redB);
    params_final_kernel<<<dim3(1), dim3(64), 0, stream>>>(redA, redB, g01, b01, g10, b10, pf);
    final_kernel<<<dim3(160, 16), dim3(256), 0, stream>>>(y1h, y2h, pf, out);
}

// Round 6
// 254.318 us; speedup vs baseline: 1.3832x; 1.3832x over previous
//
#include <hip/hip_runtime.h>
#include <hip/hip_bf16.h>

// BasicIcoS2SUpBlock — R6: R4 convA structure (cv in grid z, 16x16 tile,
// A-fragments hoisted per phase) + R5 wins (NHWC y1/y2 full-line stores,
// 14-slot weights, final-kernel transpose).
// R5 lesson: per-MFMA global weight loads in the inner loop serialized convA
// (MfmaUtil 4%, 171us). Weights must be hoisted to registers and reused.

#define CIN   64
#define COUT  32
#define HX    160
#define WX    64
#define HY    320
#define WY    128
#define NB    16
#define BN_EPS 1e-5f

typedef short s16x8 __attribute__((ext_vector_type(8)));
typedef float f32x4 __attribute__((ext_vector_type(4)));

__device__ inline void store_bf16x4(__hip_bfloat16* p, f32x4 v) {
    union { unsigned long long u; __hip_bfloat162 h[2]; } pk;
    pk.h[0] = __float22bfloat162_rn(make_float2(v[0], v[1]));
    pk.h[1] = __float22bfloat162_rn(make_float2(v[2], v[3]));
    *(unsigned long long*)p = pk.u;
}

// ---------------------------------------------------------------------------
// prep_x: x NCHW fp32 -> xt NHWC bf16 ([n][row160][col64][ci64], ci contig)
// ---------------------------------------------------------------------------
__global__ __launch_bounds__(256) void prep_x(const float* __restrict__ x,
                                              __hip_bfloat16* __restrict__ xt)
{
    __shared__ float tile[64][65];
    const int n  = blockIdx.y;
    const int p0 = blockIdx.x * 64;
    const int t  = threadIdx.x;
#pragma unroll
    for (int e = 0; e < 16; ++e) {
        int k = e * 256 + t;
        int ci = k >> 6, p = k & 63;
        tile[ci][p] = x[(n * CIN + ci) * (HX * WX) + p0 + p];
    }
    __syncthreads();
#pragma unroll
    for (int e = 0; e < 16; ++e) {
        int k = e * 256 + t;
        int p = k >> 6, ci = k & 63;
        xt[((size_t)n * (HX * WX) + p0 + p) * 64 + ci] = __float2bfloat16(tile[ci][p]);
    }
}

// ---------------------------------------------------------------------------
// prep_w: effective phase weights (bf16), 14 real slots (4/3/3/4 per phase).
// wAb: [cv(2)][slot(14)][co(32)][ci(64)]
// wBb: [tap(7)][co(32)][ci(32)]
// ---------------------------------------------------------------------------
__global__ __launch_bounds__(256) void prep_w(const float* __restrict__ w00,
                                              const float* __restrict__ w01,
                                              const float* __restrict__ w10,
                                              __hip_bfloat16* __restrict__ wAb,
                                              __hip_bfloat16* __restrict__ wBb)
{
    int t = blockIdx.x * 256 + threadIdx.x;
    if (t < 4096) {                       // convA weights
        int cv = t >> 11, u = t & 2047;
        int co = u >> 6, ci = u & 63;
        const float* w = (cv ? w10 : w00) + (co * 64 + ci) * 9;
        float a = w[0], b = w[1], c = w[3], d = w[4], e5 = w[5], f = w[7], g = w[8];
        float v[14];
        v[0] = a;              v[1] = b;          v[2] = c;      v[3] = d + e5 + f + g;
        v[4] = a + b;          v[5] = c + d + f;  v[6] = e5 + g;
        v[7] = a + c;          v[8] = b + d + e5; v[9] = f + g;
        v[10] = a + b + c + d; v[11] = e5;        v[12] = f;     v[13] = g;
#pragma unroll
        for (int s = 0; s < 14; ++s)
            wAb[(((size_t)cv * 14 + s) * 32 + co) * 64 + ci] = __float2bfloat16(v[s]);
    } else if (t < 5120) {                // convB weights (hex taps of 3x3)
        int u = t - 4096;
        int co = u >> 5, ci = u & 31;
        const float* w = w01 + (co * 32 + ci) * 9;
        const int wi[7] = {0, 1, 3, 4, 5, 7, 8};
#pragma unroll
        for (int s = 0; s < 7; ++s)
            wBb[((size_t)s * 32 + co) * 32 + ci] = __float2bfloat16(w[wi[s]]);
    }
}

// ---------------------------------------------------------------------------
// convA: conv00 (cv=0 -> y0h) / conv10 (cv=1 -> y1h), both NHWC bf16.
// Phase-decomposed, MFMA 16x16x32. Block: 16x16 x-tile -> 32x32 out px.
// A-fragments hoisted per phase (16 s16x8 regs, reused across 4 rr iters).
// LDS x-tile [18][18][ci64 pad72] = 46.6 KB. Partials -> pA[cv*640+blk][64].
// ---------------------------------------------------------------------------
__global__ __launch_bounds__(256) void convA(
    const __hip_bfloat16* __restrict__ xt, const __hip_bfloat16* __restrict__ wAb,
    __hip_bfloat16* __restrict__ y0h, __hip_bfloat16* __restrict__ y1h,
    float* __restrict__ partialsA)
{
    __shared__ short lds[324 * 72];            // 46656 B
    const int tb = blockIdx.x & 3, ta = blockIdx.x >> 2;   // ta 0..9, tb 0..3
    const int nb = blockIdx.y, cv = blockIdx.z;
    const int t = threadIdx.x, wave = t >> 6, lane = t & 63;
    const int n = lane & 15, q = lane >> 4;
    const int a0 = ta * 16, b0 = tb * 16;

    // ---- stage x tile (rows wrap mod 160, cols zero-pad) ----
    for (int idx = t; idx < 2592; idx += 256) {       // 324 chunks * 8 lanes
        int chunk = idx >> 3, sub = idx & 7;
        int rl = chunk / 18, cl = chunk - rl * 18;
        int grow = a0 - 1 + rl;
        if (grow < 0) grow += HX; else if (grow >= HX) grow -= HX;
        int gcol = b0 - 1 + cl;
        uint4 v = make_uint4(0u, 0u, 0u, 0u);
        if ((unsigned)gcol < (unsigned)WX)
            v = *(const uint4*)(xt + (((size_t)nb * HX + grow) * WX + gcol) * 64 + sub * 8);
        *(uint4*)(&lds[chunk * 72 + sub * 8]) = v;
    }
    __syncthreads();

    // per-phase tap slots (4/3/3/4), shifts
    const int off14[5] = {0, 4, 7, 10, 14};
    const int dr14[14] = {-1,-1, 0, 0,  -1, 0, 0,   0, 0, 1,   0, 0, 1, 1};
    const int dc14[14] = {-1, 0,-1, 0,   0, 0, 1,  -1, 0, 0,   0, 1, 0, 1};

    __hip_bfloat16* yp = cv ? y1h : y0h;

    f32x4 st[2], sq[2];
    st[0] = st[1] = (f32x4){0.f, 0.f, 0.f, 0.f};
    sq[0] = sq[1] = (f32x4){0.f, 0.f, 0.f, 0.f};

#pragma unroll
    for (int ph = 0; ph < 4; ++ph) {
        const int pa = ph >> 1, pb = ph & 1;
        const int s0 = off14[ph], nt = off14[ph + 1] - s0;   // 3 or 4 taps
        // ---- hoist A fragments for this phase: [tap][kc][h] ----
        s16x8 A[4][2][2];
#pragma unroll
        for (int ti = 0; ti < 4; ++ti) {
            if (ti >= nt) break;
#pragma unroll
            for (int kc = 0; kc < 2; ++kc)
#pragma unroll
                for (int h = 0; h < 2; ++h)
                    A[ti][kc][h] = *(const s16x8*)(wAb +
                        (((size_t)cv * 14 + s0 + ti) * 32 + h * 16 + n) * 64 + kc * 32 + q * 8);
        }
#pragma unroll
        for (int rr = 0; rr < 4; ++rr) {
            const int rl = wave * 4 + rr;
            s16x8 B[4][2];
#pragma unroll
            for (int ti = 0; ti < 4; ++ti) {
                if (ti >= nt) break;
                const int o = ((rl + 1 + dr14[s0 + ti]) * 18 + (n + 1 + dc14[s0 + ti])) * 72;
                B[ti][0] = *(const s16x8*)(&lds[o + q * 8]);
                B[ti][1] = *(const s16x8*)(&lds[o + 32 + q * 8]);
            }
            f32x4 acc[2];
            acc[0] = (f32x4){0.f, 0.f, 0.f, 0.f};
            acc[1] = (f32x4){0.f, 0.f, 0.f, 0.f};
#pragma unroll
            for (int ti = 0; ti < 4; ++ti) {
                if (ti >= nt) break;
#pragma unroll
                for (int kc = 0; kc < 2; ++kc)
#pragma unroll
                    for (int h = 0; h < 2; ++h)
                        acc[h] = __builtin_amdgcn_mfma_f32_16x16x32_bf16(
                            A[ti][kc][h], B[ti][kc], acc[h], 0, 0, 0);
            }
            const int i = 2 * (a0 + rl) + pa;
            const int j = 2 * b0 + pb + 2 * n;
            const size_t obase = ((((size_t)nb * HY + i) * WY + j) * 32) + q * 4;
#pragma unroll
            for (int h = 0; h < 2; ++h) {
                store_bf16x4(yp + obase + h * 16, acc[h]);
                st[h] += acc[h];
                sq[h] += acc[h] * acc[h];
            }
        }
    }

    // ---- per-block stats reduction ----
    __syncthreads();
    float* scr = (float*)lds;                 // [wave4][co32][which2]
#pragma unroll
    for (int h = 0; h < 2; ++h)
#pragma unroll
        for (int r = 0; r < 4; ++r) {
            float s = st[h][r], qv = sq[h][r];
#pragma unroll
            for (int m = 1; m < 16; m <<= 1) {
                s  += __shfl_xor(s, m, 16);
                qv += __shfl_xor(qv, m, 16);
            }
            if (n == 0) {
                const int co = h * 16 + q * 4 + r;
                scr[(wave * 32 + co) * 2]     = s;
                scr[(wave * 32 + co) * 2 + 1] = qv;
            }
        }
    __syncthreads();
    if (t < 64) {
        const int co = t & 31, which = t >> 5;
        float s = 0.f;
#pragma unroll
        for (int w = 0; w < 4; ++w) s += scr[(w * 32 + co) * 2 + which];
        const int blk = nb * 40 + blockIdx.x;          // 0..639
        partialsA[((size_t)cv * 640 + blk) * 64 + which * 32 + co] = s;
    }
}

// ---------------------------------------------------------------------------
// reduce16: block b reduces src[b*16 .. b*16+15][64] -> dst[b][64]
// ---------------------------------------------------------------------------
__global__ __launch_bounds__(256) void reduce16(const float* __restrict__ src,
                                                float* __restrict__ dst)
{
    __shared__ float red[4][64];
    const int t = threadIdx.x, c = t & 63, seg = t >> 6;
    const float* s = src + (size_t)blockIdx.x * 16 * 64;
    float acc = 0.f;
#pragma unroll
    for (int r = 0; r < 4; ++r) acc += s[(seg + r * 4) * 64 + c];
    red[seg][c] = acc;
    __syncthreads();
    if (t < 64)
        dst[(size_t)blockIdx.x * 64 + t] = red[0][t] + red[1][t] + red[2][t] + red[3][t];
}

// ---------------------------------------------------------------------------
// params_h: redA rows 0..39 (conv00) -> BN scale/shift for h. phs: [s32, t32]
// ---------------------------------------------------------------------------
__global__ void params_h_kernel(const float* __restrict__ redA,
                                const float* __restrict__ g00,
                                const float* __restrict__ b00,
                                float* __restrict__ phs)
{
    __shared__ float tot[64];
    const int t = threadIdx.x;
    float s = 0.f;
    for (int b = 0; b < 40; ++b) s += redA[b * 64 + t];
    tot[t] = s;
    __syncthreads();
    if (t < 32) {
        const float nf = (float)(NB * HY * WY);
        float mean = tot[t] / nf;
        float var  = tot[32 + t] / nf - mean * mean;
        float sc = g00[t] * rsqrtf(var + BN_EPS);
        phs[t] = sc;
        phs[32 + t] = b00[t] - mean * sc;
    }
}

// ---------------------------------------------------------------------------
// convB: conv01 on h = relu(bn(y0)) (BN+ReLU fused into bf16 staging).
// Block: 8x32 out-tile, all 32 co. LDS [10][34][ci32 pad40] = 27.2 KB.
// A-fragments hoisted before loop. Output y2 NHWC bf16. Partials -> pB.
// ---------------------------------------------------------------------------
__global__ __launch_bounds__(256) void convB(
    const __hip_bfloat16* __restrict__ y0h, const __hip_bfloat16* __restrict__ wBb,
    const float* __restrict__ phs, __hip_bfloat16* __restrict__ y2h,
    float* __restrict__ partialsB)
{
    __shared__ short lds[340 * 40];            // 27200 B
    const int tj = blockIdx.x & 3, ti = blockIdx.x >> 2;   // ti 0..39, tj 0..3
    const int nb = blockIdx.y;
    const int t = threadIdx.x, wave = t >> 6, lane = t & 63;
    const int n = lane & 15, q = lane >> 4;
    const int i0 = ti * 8, j0 = tj * 32;

    // BN params for this thread's staged ci octet (sub = t&3 stays fixed)
    const int cis = (t & 3) * 8;
    float sv[8], tv[8];
#pragma unroll
    for (int e = 0; e < 8; ++e) { sv[e] = phs[cis + e]; tv[e] = phs[32 + cis + e]; }

    // ---- stage h tile ----
    for (int idx = t; idx < 1360; idx += 256) {      // 340 chunks * 4 lanes
        int chunk = idx >> 2, sub = idx & 3;
        int rl = chunk / 34, cl = chunk - rl * 34;
        int grow = i0 - 1 + rl;
        if (grow < 0) grow += HY; else if (grow >= HY) grow -= HY;
        int gcol = j0 - 1 + cl;
        uint4 w = make_uint4(0u, 0u, 0u, 0u);
        if ((unsigned)gcol < (unsigned)WY) {
            uint4 v = *(const uint4*)(y0h + (((size_t)nb * HY + grow) * WY + gcol) * 32 + sub * 8);
            unsigned* vi = (unsigned*)&v;
            unsigned* wi = (unsigned*)&w;
#pragma unroll
            for (int k = 0; k < 4; ++k) {
                unsigned u = vi[k];
                float f0 = __uint_as_float(u << 16);
                float f1 = __uint_as_float(u & 0xffff0000u);
                f0 = fmaxf(fmaf(f0, sv[2 * k], tv[2 * k]), 0.f);
                f1 = fmaxf(fmaf(f1, sv[2 * k + 1], tv[2 * k + 1]), 0.f);
                union { __hip_bfloat162 b2; unsigned u32; } cvt;
                cvt.b2 = __float22bfloat162_rn(make_float2(f0, f1));
                wi[k] = cvt.u32;
            }
        }
        *(uint4*)(&lds[chunk * 40 + sub * 8]) = w;
    }
    __syncthreads();

    // A fragments [tap][h] (persist: 14 x 4 VGPRs)
    s16x8 A[7][2];
#pragma unroll
    for (int s = 0; s < 7; ++s)
#pragma unroll
        for (int h = 0; h < 2; ++h)
            A[s][h] = *(const s16x8*)(wBb + ((size_t)s * 32 + h * 16 + n) * 32 + q * 8);

    const int dr7[7] = {-1, -1, 0, 0, 0, 1, 1};
    const int dc7[7] = {-1,  0,-1, 0, 1, 0, 1};

    f32x4 st[2], sq[2];
    st[0] = st[1] = (f32x4){0.f, 0.f, 0.f, 0.f};
    sq[0] = sq[1] = (f32x4){0.f, 0.f, 0.f, 0.f};

#pragma unroll
    for (int rr = 0; rr < 2; ++rr) {
        const int rl = wave * 2 + rr;
#pragma unroll
        for (int cg = 0; cg < 2; ++cg) {
            s16x8 B[7];
#pragma unroll
            for (int s = 0; s < 7; ++s)
                B[s] = *(const s16x8*)(&lds[((rl + 1 + dr7[s]) * 34 +
                                             (cg * 16 + n + 1 + dc7[s])) * 40 + q * 8]);
            f32x4 acc[2];
            acc[0] = (f32x4){0.f, 0.f, 0.f, 0.f};
            acc[1] = (f32x4){0.f, 0.f, 0.f, 0.f};
#pragma unroll
            for (int s = 0; s < 7; ++s)
#pragma unroll
                for (int h = 0; h < 2; ++h)
                    acc[h] = __builtin_amdgcn_mfma_f32_16x16x32_bf16(
                        A[s][h], B[s], acc[h], 0, 0, 0);
            const int i = i0 + rl;
            const int j = j0 + cg * 16 + n;
            const size_t obase = ((((size_t)nb * HY + i) * WY + j) * 32) + q * 4;
#pragma unroll
            for (int h = 0; h < 2; ++h) {
                store_bf16x4(y2h + obase + h * 16, acc[h]);
                st[h] += acc[h];
                sq[h] += acc[h] * acc[h];
            }
        }
    }

    __syncthreads();
    float* scr = (float*)lds;                 // [wave4][co32][which2]
#pragma unroll
    for (int h = 0; h < 2; ++h)
#pragma unroll
        for (int r = 0; r < 4; ++r) {
            float s = st[h][r], qv = sq[h][r];
#pragma unroll
            for (int m = 1; m < 16; m <<= 1) {
                s  += __shfl_xor(s, m, 16);
                qv += __shfl_xor(qv, m, 16);
            }
            if (n == 0) {
                const int co = h * 16 + q * 4 + r;
                scr[(wave * 32 + co) * 2]     = s;
                scr[(wave * 32 + co) * 2 + 1] = qv;
            }
        }
    __syncthreads();
    if (t < 64) {
        const int co = t & 31, which = t >> 5;
        float s = 0.f;
#pragma unroll
        for (int w = 0; w < 4; ++w) s += scr[(w * 32 + co) * 2 + which];
        const int blk = nb * 160 + blockIdx.x;          // 0..2559
        partialsB[(size_t)blk * 64 + which * 32 + co] = s;
    }
}

// ---------------------------------------------------------------------------
// params_final: redA rows 40..79 (conv10) + redB rows 0..159 (conv01) -> pf
// pf: [s1[32], t1[32], s2[32], t2[32]]
// ---------------------------------------------------------------------------
__global__ void params_final_kernel(const float* __restrict__ redA,
                                    const float* __restrict__ redB,
                                    const float* __restrict__ g01,
                                    const float* __restrict__ b01,
                                    const float* __restrict__ g10,
                                    const float* __restrict__ b10,
                                    float* __restrict__ pf)
{
    __shared__ float tot1[64], tot2[64];
    const int t = threadIdx.x;
    float s1 = 0.f, s2 = 0.f;
    for (int b = 0; b < 40; ++b)  s1 += redA[(40 + b) * 64 + t];
    for (int b = 0; b < 160; ++b) s2 += redB[b * 64 + t];
    tot1[t] = s1; tot2[t] = s2;
    __syncthreads();
    if (t < 32) {
        const float nf = (float)(NB * HY * WY);
        float m1 = tot1[t] / nf;
        float v1 = tot1[32 + t] / nf - m1 * m1;
        float sc1 = g10[t] * rsqrtf(v1 + BN_EPS);
        pf[t] = sc1;
        pf[32 + t] = b10[t] - m1 * sc1;
        float m2 = tot2[t] / nf;
        float v2 = tot2[32 + t] / nf - m2 * m2;
        float sc2 = g01[t] * rsqrtf(v2 + BN_EPS);
        pf[64 + t] = sc2;
        pf[96 + t] = b01[t] - m2 * sc2;
    }
}

// ---------------------------------------------------------------------------
// final: out = relu(bn(y2) + bn(y1)) with NHWC->NCHW transpose via LDS.
// Block: (nb, 2 rows); reads y1h/y2h NHWC coalesced, writes out NCHW float4.
// ---------------------------------------------------------------------------
__global__ __launch_bounds__(256) void final_kernel(
    const __hip_bfloat16* __restrict__ y1h, const __hip_bfloat16* __restrict__ y2h,
    const float* __restrict__ pf, float* __restrict__ out)
{
    __shared__ float ldsf[32 * 132];
    const int nb = blockIdx.y;
    const int i0 = blockIdx.x * 2;
    const int t = threadIdx.x;
    const int c8 = (t & 3) * 8;                 // this thread's co octet (fixed)

    float P1s[8], P1t[8], P2s[8], P2t[8];
#pragma unroll
    for (int e = 0; e < 8; ++e) {
        P1s[e] = pf[c8 + e];      P1t[e] = pf[32 + c8 + e];
        P2s[e] = pf[64 + c8 + e]; P2t[e] = pf[96 + c8 + e];
    }

    for (int row = 0; row < 2; ++row) {
        const int i = i0 + row;
        const size_t base = (((size_t)nb * HY + i) * WY) * 32;
        if (row) __syncthreads();
#pragma unroll
        for (int rep = 0; rep < 2; ++rep) {
            const int idx = rep * 256 + t;      // 0..511
            const int j = idx >> 2;             // 0..127
            uint4 a = *(const uint4*)(y2h + base + (size_t)j * 32 + c8);
            uint4 d = *(const uint4*)(y1h + base + (size_t)j * 32 + c8);
            const unsigned* ai = (const unsigned*)&a;
            const unsigned* di = (const unsigned*)&d;
#pragma unroll
            for (int k = 0; k < 4; ++k) {
                float a0 = __uint_as_float(ai[k] << 16);
                float a1 = __uint_as_float(ai[k] & 0xffff0000u);
                float d0 = __uint_as_float(di[k] << 16);
                float d1 = __uint_as_float(di[k] & 0xffff0000u);
                float r0 = fmaf(a0, P2s[2 * k], P2t[2 * k]) + fmaf(d0, P1s[2 * k], P1t[2 * k]);
                float r1 = fmaf(a1, P2s[2 * k + 1], P2t[2 * k + 1]) + fmaf(d1, P1s[2 * k + 1], P1t[2 * k + 1]);
                ldsf[(c8 + 2 * k) * 132 + j]     = r0 > 0.f ? r0 : 0.f;
                ldsf[(c8 + 2 * k + 1) * 132 + j] = r1 > 0.f ? r1 : 0.f;
            }
        }
        __syncthreads();
#pragma unroll
        for (int rep = 0; rep < 4; ++rep) {
            const int idx = rep * 256 + t;      // 0..1023
            const int co = idx >> 5, jg = (idx & 31) * 4;
            float4 v = *(float4*)(&ldsf[co * 132 + jg]);
            *(float4*)(out + (((size_t)nb * 32 + co) * HY + i) * WY + jg) = v;
        }
    }
}

// ---------------------------------------------------------------------------
extern "C" void kernel_launch(void* const* d_in, const int* in_sizes, int n_in,
                              void* d_out, int out_size, void* d_ws, size_t ws_size,
                              hipStream_t stream)
{
    (void)in_sizes; (void)n_in; (void)out_size; (void)ws_size;
    const float* x   = (const float*)d_in[0];
    const float* w00 = (const float*)d_in[1];
    const float* w01 = (const float*)d_in[2];
    const float* w10 = (const float*)d_in[3];
    const float* g00 = (const float*)d_in[4];
    const float* b00 = (const float*)d_in[5];
    const float* g01 = (const float*)d_in[6];
    const float* b01 = (const float*)d_in[7];
    const float* g10 = (const float*)d_in[8];
    const float* b10 = (const float*)d_in[9];
    float* out = (float*)d_out;

    // workspace (byte offsets, all 256B-aligned)
    char* ws = (char*)d_ws;
    const size_t NPLANE = (size_t)NB * COUT * HY * WY;       // 20,971,520
    __hip_bfloat16* y1h  = (__hip_bfloat16*)ws;               ws += NPLANE * 2;
    __hip_bfloat16* y2h  = (__hip_bfloat16*)ws;               ws += NPLANE * 2;
    __hip_bfloat16* y0h  = (__hip_bfloat16*)ws;               ws += NPLANE * 2;
    __hip_bfloat16* xt   = (__hip_bfloat16*)ws;               ws += (size_t)NB * CIN * HX * WX * 2;
    __hip_bfloat16* wAb  = (__hip_bfloat16*)ws;               ws += 2 * 14 * 32 * 64 * 2;
    __hip_bfloat16* wBb  = (__hip_bfloat16*)ws;               ws += 7 * 32 * 32 * 2;
    float*          pA   = (float*)ws;                        ws += 2 * 640 * 64 * 4;
    float*          pB   = (float*)ws;                        ws += 2560 * 64 * 4;
    float*          redA = (float*)ws;                        ws += 80 * 64 * 4;
    float*          redB = (float*)ws;                        ws += 160 * 64 * 4;
    float*          phs  = (float*)ws;                        ws += 256;
    float*          pf   = (float*)ws;

    prep_x<<<dim3(160, 16), dim3(256), 0, stream>>>(x, xt);
    prep_w<<<dim3(20), dim3(256), 0, stream>>>(w00, w01, w10, wAb, wBb);
    convA<<<dim3(40, 16, 2), dim3(256), 0, stream>>>(xt, wAb, y0h, y1h, pA);
    reduce16<<<dim3(80), dim3(256), 0, stream>>>(pA, redA);
    params_h_kernel<<<dim3(1), dim3(64), 0, stream>>>(redA, g00, b00, phs);
    convB<<<dim3(160, 16), dim3(256), 0, stream>>>(y0h, wBb, phs, y2h, pB);
    reduce16<<<dim3(160), dim3(256), 0, stream>>>(pB, redB);
    params_final_kernel<<<dim3(1), dim3(64), 0, stream>>>(redA, redB, g01, b01, g10, b10, pf);
    final_kernel<<<dim3(160, 16), dim3(256), 0, stream>>>(y1h, y2h, pf, out);
}